// Round 4
// baseline (676.505 us; speedup 1.0000x reference)
//
#include <hip/hip_runtime.h>
#include <hip/hip_bf16.h>
#include <math.h>

// Problem constants
#define B_ 4
#define L_ 4096
#define E_ 1024
#define H_ 16
#define D_ 64
#define M_ (B_*L_)   // 16384 rows

typedef __attribute__((ext_vector_type(8))) short s8;     // 8 bf16 (4 VGPRs)
typedef __attribute__((ext_vector_type(4))) float f4;     // MFMA C/D

// g(x) = (softplus(5x)/5)^2 via HW v_exp/v_log; clamp z<=60 (no overflow).
__device__ __forceinline__ float gfun(float x) {
  float z = fminf(5.0f * x, 60.0f);
  float sp = 0.2f * __logf(1.0f + __expf(z));
  return sp * sp;
}

__device__ __forceinline__ unsigned short f2bf(float v) {
  __hip_bfloat16 h = __float2bfloat16(v);
  return *reinterpret_cast<unsigned short*>(&h);
}
__device__ __forceinline__ float bf2f(unsigned short u) {
  __hip_bfloat16 h = *reinterpret_cast<__hip_bfloat16*>(&u);
  return __bfloat162float(h);
}

// async global->LDS, 16 B per lane
__device__ __forceinline__ void gload16(const void* g, void* l) {
  __builtin_amdgcn_global_load_lds(
      (const __attribute__((address_space(1))) void*)g,
      (__attribute__((address_space(3))) void*)l, 16, 0, 0);
}

// ---------------------------------------------------------------------------
// Prep 1: split x into bf16 hi|lo -> Ah [16384,2048], AND accumulate per-b
// column sums (xsum[b][e]) for the q-global path.  grid 256 blocks x 256 thr;
// block = 64 rows of one b; thread = one float4 column group.
// ---------------------------------------------------------------------------
__global__ __launch_bounds__(256) void split_x(
    const float* __restrict__ x, unsigned short* __restrict__ Ah,
    float* __restrict__ xsum)
{
  int blk = blockIdx.x, t = threadIdx.x;
  int r0 = blk * 64, b = r0 >> 12;
  int c4 = t * 4;
  float4 cs = {0.f, 0.f, 0.f, 0.f};
  for (int r = 0; r < 64; ++r) {
    int row = r0 + r;
    float4 x4 = *(const float4*)(x + (size_t)row * E_ + c4);
    ushort4 hi, lo;
    unsigned short h;
    h = f2bf(x4.x); hi.x = h; lo.x = f2bf(x4.x - bf2f(h));
    h = f2bf(x4.y); hi.y = h; lo.y = f2bf(x4.y - bf2f(h));
    h = f2bf(x4.z); hi.z = h; lo.z = f2bf(x4.z - bf2f(h));
    h = f2bf(x4.w); hi.w = h; lo.w = f2bf(x4.w - bf2f(h));
    *(ushort4*)&Ah[(size_t)row * 2048 + c4]        = hi;
    *(ushort4*)&Ah[(size_t)row * 2048 + 1024 + c4] = lo;
    cs.x += x4.x; cs.y += x4.y; cs.z += x4.z; cs.w += x4.w;
  }
  atomicAdd(&xsum[b * E_ + c4 + 0], cs.x);
  atomicAdd(&xsum[b * E_ + c4 + 1], cs.y);
  atomicAdd(&xsum[b * E_ + c4 + 2], cs.z);
  atomicAdd(&xsum[b * E_ + c4 + 3], cs.w);
}

// ---------------------------------------------------------------------------
// Prep 2: transpose + split each W -> Bt[z] [1024,2048] bf16 (hi|lo).
// z==0 blocks also finish qg: qg[b][n] += (sum_k xsum[b][k]*Wq[k][n])/(L*8)
// (+ bq[n]/8 from the k0==0 blocks).  Wq tile already in LDS.
// ---------------------------------------------------------------------------
__global__ __launch_bounds__(256) void split_wT(
    const float* __restrict__ Wq, const float* __restrict__ Wk,
    const float* __restrict__ Wv, const float* __restrict__ bq,
    const float* __restrict__ xsum,
    unsigned short* __restrict__ Bt, float* __restrict__ qg)
{
  int z = blockIdx.z;
  const float* W = (z == 0) ? Wq : (z == 1) ? Wk : Wv;
  __shared__ float tile[32][33];
  int t = threadIdx.x;
  int tx = t & 31, ty = t >> 5;                    // ty 0..7
  int k0 = blockIdx.x * 32, n0 = blockIdx.y * 32;
  #pragma unroll
  for (int i = 0; i < 4; ++i)
    tile[ty + i*8][tx] = W[(size_t)(k0 + ty + i*8) * 1024 + n0 + tx];
  __syncthreads();
  unsigned short* Bz = Bt + (size_t)z * 2097152;
  #pragma unroll
  for (int i = 0; i < 4; ++i) {
    int n = n0 + ty + i*8, kk = k0 + tx;
    float v = tile[tx][ty + i*8];
    unsigned short h = f2bf(v);
    Bz[(size_t)n * 2048 + kk]        = h;
    Bz[(size_t)n * 2048 + 1024 + kk] = f2bf(v - bf2f(h));
  }
  if (z == 0 && t < 128) {
    int n = t & 31, b = t >> 5;
    float dot = 0.f;
    #pragma unroll
    for (int kk = 0; kk < 32; ++kk)
      dot += xsum[b * E_ + k0 + kk] * tile[kk][n];
    float val = dot * (1.0f / (L_ * 8.0f));
    if (k0 == 0) val += bq[n0 + n] * 0.125f;
    atomicAdd(&qg[b * E_ + n0 + n], val);
  }
}

// ---------------------------------------------------------------------------
// Kernel 1: fused QKV, 256x256-tile / BK=64 / 8-wave / 8-phase schedule
// (m201-template: T2 XOR-swizzle + T3/T4 counted-vmcnt pipeline + T5 setprio).
//
// Grid: 768 blocks x 512 thr = 1 blk/CU (128 KiB LDS), exactly 3 rounds.
// XCD swizzle: xc = li&7; per-XCD order z-outer (32 blocks = 8 m x 4 n per z)
// so one z's B matrix (4 MB) stays L2-resident while A streams.
//
// LDS (bytes): A0 [0,32K) A1 [32K,64K) B0 [64K,96K) B1 [96K,128K)
// each tile = [256 rows][64 k] bf16, row = 128 B, col-slot (16 B) swizzled by
// slot ^= row&7.  global_load_lds writes linearly -> inverse swizzle applied
// to the per-lane GLOBAL source column; ds_read applies the same XOR (#21).
//
// Phase plan:
//   P1: LDA(0)+LDB(0)+LDB(1) [16 ds_read] -> bar -> lgkm0 -> Q(0,0) -> bar
//   P2: STAGE_B(t+2)  [buf.B dead at P1-end]  -> bar -> Q(0,1) -> bar
//   P3: LDA(1) [8 ds_read] -> bar -> lgkm0 -> Q(1,0) -> bar
//   P4: STAGE_A(t+2)  [buf.A dead at P3-end]  -> bar -> Q(1,1) -> vmcnt -> bar
// Ledger: prologue B0 A0 B1 A1 (16 loads) -> vmcnt(8) = tile0 landed.
//   end-P4 checkpoint vmcnt(8): leaves exactly {B,A}(t+2) in flight => tile
//   t+1 fully landed.  Peeled last iteration: no stages, vmcnt(0).
//
// z==1 epilogue: wave tile = 128 rows x one head; logit = qg . k via 4-step
// fr-butterfly; aexp=exp(logit), denom += (fr==0 lanes).
// ---------------------------------------------------------------------------
#define PRIO1() __builtin_amdgcn_s_setprio(1)
#define PRIO0() __builtin_amdgcn_s_setprio(0)
#define BARR() do { asm volatile("" ::: "memory"); \
                    __builtin_amdgcn_s_barrier(); \
                    asm volatile("" ::: "memory"); } while (0)
#define WAITL0() asm volatile("s_waitcnt lgkmcnt(0)" ::: "memory")
#define WAITV(n) asm volatile("s_waitcnt vmcnt(" n ")" ::: "memory")

#define STAGE_A(buf, kofs) do { \
  const unsigned short* g_ = gA + (kofs); \
  char* d_ = dA0 + (buf) * 32768; \
  gload16(g_,          d_); \
  gload16(g_ + 131072, d_ +  8192); \
  gload16(g_ + 262144, d_ + 16384); \
  gload16(g_ + 393216, d_ + 24576); \
} while (0)

#define STAGE_B(buf, kofs) do { \
  const unsigned short* g_ = gB + (kofs); \
  char* d_ = dB0 + (buf) * 32768; \
  gload16(g_,          d_); \
  gload16(g_ + 131072, d_ +  8192); \
  gload16(g_ + 262144, d_ + 16384); \
  gload16(g_ + 393216, d_ + 24576); \
} while (0)

#define LDA(buf, mh) do { \
  const char* p_ = shb + (buf) * 32768 + arow + (mh) * 8192; \
  _Pragma("unroll") \
  for (int ii = 0; ii < 4; ++ii) { \
    aF[ii][0] = *(const s8*)(p_ + ii * 2048 + c0); \
    aF[ii][1] = *(const s8*)(p_ + ii * 2048 + c1); \
  } \
} while (0)

#define LDB(buf, nh) do { \
  const char* p_ = shb + 65536 + (buf) * 32768 + brow + (nh) * 4096; \
  _Pragma("unroll") \
  for (int jj = 0; jj < 2; ++jj) { \
    bF[(nh)*2+jj][0] = *(const s8*)(p_ + jj * 2048 + c0); \
    bF[(nh)*2+jj][1] = *(const s8*)(p_ + jj * 2048 + c1); \
  } \
} while (0)

#define MFMAQ(mh, nh) do { \
  _Pragma("unroll") \
  for (int ii = 0; ii < 4; ++ii) \
    _Pragma("unroll") \
    for (int jj = 0; jj < 2; ++jj) { \
      acc[(mh)*4+ii][(nh)*2+jj] = __builtin_amdgcn_mfma_f32_16x16x32_bf16( \
          aF[ii][0], bF[(nh)*2+jj][0], acc[(mh)*4+ii][(nh)*2+jj], 0, 0, 0); \
      acc[(mh)*4+ii][(nh)*2+jj] = __builtin_amdgcn_mfma_f32_16x16x32_bf16( \
          aF[ii][1], bF[(nh)*2+jj][1], acc[(mh)*4+ii][(nh)*2+jj], 0, 0, 0); \
    } \
} while (0)

// 4 phases for one K-tile in buffer `buf`; stages (if doStage) target tile
// kofs pair; vmN = vmcnt immediate (string) at end-P4.
#define TILE4(buf, doStage, kB_, kA_, vmN) do { \
  /* P1: aF<-half0, bF<-both halves */ \
  LDA(buf, 0); LDB(buf, 0); LDB(buf, 1); \
  BARR(); WAITL0(); \
  PRIO1(); MFMAQ(0, 0); PRIO0(); \
  BARR(); \
  /* P2: stage B(t+2); Q(0,1) */ \
  if (doStage) STAGE_B(buf, kB_); \
  BARR(); \
  PRIO1(); MFMAQ(0, 1); PRIO0(); \
  BARR(); \
  /* P3: aF<-half1; Q(1,0) */ \
  LDA(buf, 1); \
  BARR(); WAITL0(); \
  PRIO1(); MFMAQ(1, 0); PRIO0(); \
  BARR(); \
  /* P4: stage A(t+2); Q(1,1); checkpoint */ \
  if (doStage) STAGE_A(buf, kA_); \
  BARR(); \
  PRIO1(); MFMAQ(1, 1); PRIO0(); \
  WAITV(vmN); \
  BARR(); \
} while (0)

__global__ __launch_bounds__(512, 2) void qkv_mfma(
    const unsigned short* __restrict__ Ah, const unsigned short* __restrict__ Bt,
    const float* __restrict__ bq, const float* __restrict__ bk,
    const float* __restrict__ bv, const float* __restrict__ qg,
    float* __restrict__ aexp, float* __restrict__ denom,
    float* __restrict__ qo, float* __restrict__ ko, float* __restrict__ vo)
{
  __shared__ unsigned short sh[65536];   // 128 KiB

  const int t  = threadIdx.x;
  const int li = blockIdx.x;            // 0..767
  const int xc = li & 7;
  const int idx = li >> 3;              // 0..95 within XCD
  const int z   = idx >> 5;             // 0..2 (z-outer per XCD)
  const int rem = idx & 31;
  const int bm = (xc * 8 + (rem >> 2)) * 256;
  const int bn = (rem & 3) * 256;

  const float* bias = (z == 0) ? bq : (z == 1) ? bk : bv;
  float* out = (z == 0) ? qo : (z == 1) ? ko : vo;
  const unsigned short* Bz = Bt + (size_t)z * 2097152;

  // staging: thread t writes LDS bytes [region + t*16); physical (row,slot) =
  // (t>>3 + 64*ld, t&7).  Source column is the inverse-swizzled slot.
  const int srow = t >> 3;
  const int scol = ((t & 7) ^ (srow & 7)) * 8;        // elements
  const unsigned short* gA = Ah + (size_t)(bm + srow) * 2048 + scol;
  const unsigned short* gB = Bz + (size_t)(bn + srow) * 2048 + scol;
  char* const shb = (char*)sh;
  char* const dA0 = shb +         t * 16;
  char* const dB0 = shb + 65536 + t * 16;

  // compute mapping: 8 waves = 2M x 4N, wave tile 128x64
  const int lane = t & 63, wid = t >> 6;
  const int wm = wid >> 2, wn = wid & 3;
  const int fr = lane & 15, fq = lane >> 4;
  const int c0 = ((fq)     ^ (fr & 7)) * 16;          // kk=0 swizzled col byte
  const int c1 = ((fq + 4) ^ (fr & 7)) * 16;          // kk=1
  const int arow = (wm * 128 + fr) * 128;
  const int brow = (wn *  64 + fr) * 128;

  f4 acc[8][4] = {};
  s8 aF[4][2], bF[4][2];

  // prologue: tiles 0 (buf0) and 1 (buf1)
  STAGE_B(0, 0);  STAGE_A(0, 0);
  STAGE_B(1, 64); STAGE_A(1, 64);
  WAITV("8");
  BARR();

  // K' = 3072 = 48 tiles of 64; seg map: A cols [hi,hi,lo], B cols [hi,lo,hi]
  #pragma unroll 1
  for (int it = 0; it < 23; ++it) {
    const int t2 = 2 * it + 2, t3 = 2 * it + 3;
    const int kA2 = (t2 < 16) ? t2 * 64 : t2 * 64 - 1024;
    const int kB2 = (t2 < 32) ? t2 * 64 : t2 * 64 - 2048;
    const int kA3 = (t3 < 16) ? t3 * 64 : t3 * 64 - 1024;
    const int kB3 = (t3 < 32) ? t3 * 64 : t3 * 64 - 2048;
    TILE4(0, true, kB2, kA2, "8");
    TILE4(1, true, kB3, kA3, "8");
  }
  // peeled final iteration: tiles 46, 47 — no stages, drain
  TILE4(0, false, 0, 0, "0");
  TILE4(1, false, 0, 0, "0");

  // epilogue: C += bias, store
  float bv4[4];
  #pragma unroll
  for (int j = 0; j < 4; ++j) bv4[j] = bias[bn + wn * 64 + j * 16 + fr];
  #pragma unroll
  for (int i = 0; i < 8; ++i) {
    const int mrow = bm + wm * 128 + i * 16 + fq * 4;
    #pragma unroll
    for (int j = 0; j < 4; ++j) {
      const int ncol = bn + wn * 64 + j * 16 + fr;
      #pragma unroll
      for (int r = 0; r < 4; ++r)
        out[(size_t)(mrow + r) * E_ + ncol] = acc[i][j][r] + bv4[j];
    }
  }

  if (z == 1) {
    // alpha epilogue: this wave's 128 rows x head (bn>>6)+wn
    const int b_ = bm >> 12;
    const int h  = (bn >> 6) + wn;
    const int bh = b_ * 16 + h;
    float qgv[4];
    #pragma unroll
    for (int j = 0; j < 4; ++j) qgv[j] = qg[bh * 64 + j * 16 + fr];
    float partial[8][4];
    #pragma unroll
    for (int i = 0; i < 8; ++i)
      #pragma unroll
      for (int r = 0; r < 4; ++r) {
        float p = 0.f;
        #pragma unroll
        for (int j = 0; j < 4; ++j)
          p += qgv[j] * (acc[i][j][r] + bv4[j]);
        p += __shfl_xor(p, 1);
        p += __shfl_xor(p, 2);
        p += __shfl_xor(p, 4);
        p += __shfl_xor(p, 8);
        partial[i][r] = p;
      }
    if (fr == 0) {
      const int lbase = (bm & 4095) + wm * 128 + fq * 4;
      float s = 0.f;
      #pragma unroll
      for (int i = 0; i < 8; ++i)
        #pragma unroll
        for (int r = 0; r < 4; ++r) {
          float e = __expf(partial[i][r]);
          aexp[(size_t)bh * 4096 + lbase + i * 16 + r] = e;
          s += e;
        }
      atomicAdd(&denom[bh], s);
    }
  }
}

// ---------------------------------------------------------------------------
// Kernel 2 (R4 rewrite): KV-state partials via MFMA.
// grid (64 bh, 32 chunks of 128 l), 256 thr.  Per block:
//   Phase 1 (producer): load k,v [128 l][64 d] f32; av = aexp*L/denom;
//     gk=gfun(k*av), gmk=gfun(-k*av); split bf16 hi|lo; store TRANSPOSED to
//     LDS: GT[64 d][256] = gk^T (cols 0..127 hi | 128..255 lo), MT = gmk^T,
//     VT[64 vv][256] = v^T.  XOR swizzle: 16B-slot ^= row&7 (write+read both
//     sides in-kernel).  Thread = (l-pair, d-quarter): packs ushort2{l0,l1},
//     no cross-lane exchange needed.
//   Phase 2: one __syncthreads.
//   Phase 3 (MFMA): 4 waves = (state s, d-half dh).  acc[2][4] f4.
//     K' = 3*128 (split-bf16 seg map A:[hi,hi,lo] B:[hi,lo,hi]), 12 ksteps,
//     per kstep: 2 A-frags + 4 B-frags (b128) -> 8 mfma_16x16x32_bf16.
//     C layout row=fq*4+r col=fr (same verified mapping as qkv).
//   ksum/kmsum: waves 0-1 row-sum GT/MT rows (hi+lo slots) -> kpart/kmpart.
// Output format (32 partials, [d*64+vv]) unchanged -> state_reduce untouched.
// FLOPs move from 4.3G vector-MAC (55 us floor) to 25.8 GF MFMA (~2% peak);
// kernel becomes HBM-bound (~195 MB).
// ---------------------------------------------------------------------------
__global__ __launch_bounds__(256) void state_part(
    const float* __restrict__ k, const float* __restrict__ v,
    const float* __restrict__ aexp, const float* __restrict__ denom,
    float* __restrict__ Spart, float* __restrict__ SMpart,
    float* __restrict__ kpart, float* __restrict__ kmpart)
{
  __shared__ unsigned short lds[49152];   // GT[64][256] | MT | VT  (96 KiB)
  const int bh = blockIdx.x, b = bh >> 4, h = bh & 15;
  const int c = blockIdx.y;               // 0..31
  const int l0 = c * 128;
  const float scale = (float)L_ / denom[bh];
  const int t = threadIdx.x;

  // ---- Phase 1: producer ----
  {
    const int lp = t >> 2, c4 = t & 3;    // l-pair 0..63, d-quarter-lane 0..3
    const size_t r0 = (size_t)(b * L_ + l0 + 2 * lp) * E_ + h * 64;
    float4 k0[4], k1[4], v0[4], v1[4];
    #pragma unroll
    for (int i = 0; i < 4; ++i) {
      const int col = c4 * 4 + i * 16;
      k0[i] = *(const float4*)(k + r0 + col);
      k1[i] = *(const float4*)(k + r0 + E_ + col);
      v0[i] = *(const float4*)(v + r0 + col);
      v1[i] = *(const float4*)(v + r0 + E_ + col);
    }
    const float av0 = aexp[(size_t)bh * L_ + l0 + 2 * lp]     * scale;
    const float av1 = aexp[(size_t)bh * L_ + l0 + 2 * lp + 1] * scale;
    const int usl = 2 * lp;               // logical ushort col (hi); +128 = lo
    #pragma unroll
    for (int i = 0; i < 4; ++i) {
      const float ke[4] = {k0[i].x, k0[i].y, k0[i].z, k0[i].w};
      const float ko[4] = {k1[i].x, k1[i].y, k1[i].z, k1[i].w};
      const float ve[4] = {v0[i].x, v0[i].y, v0[i].z, v0[i].w};
      const float vo[4] = {v1[i].x, v1[i].y, v1[i].z, v1[i].w};
      #pragma unroll
      for (int j = 0; j < 4; ++j) {
        const int d  = c4 * 4 + i * 16 + j;
        const int rb = d * 256, x7 = d & 7;
        const int ph = rb + (((usl      ) >> 3) ^ x7) * 8 + (usl & 7);
        const int pl = rb + (((usl + 128) >> 3) ^ x7) * 8 + (usl & 7);
        const float ge = gfun( ke[j] * av0), go = gfun( ko[j] * av1);
        const float me = gfun(-ke[j] * av0), mo = gfun(-ko[j] * av1);
        unsigned short eh, oh;
        unsigned int w;
        // gk -> GT
        eh = f2bf(ge); oh = f2bf(go);
        w = (unsigned)eh | ((unsigned)oh << 16);
        *(unsigned int*)&lds[ph] = w;
        eh = f2bf(ge - bf2f(eh)); oh = f2bf(go - bf2f(oh));
        w = (unsigned)eh | ((unsigned)oh << 16);
        *(unsigned int*)&lds[pl] = w;
        // gmk -> MT
        eh = f2bf(me); oh = f2bf(mo);
        w = (unsigned)eh | ((unsigned)oh << 16);
        *(unsigned int*)&lds[16384 + ph] = w;
        eh = f2bf(me - bf2f(eh)); oh = f2bf(mo - bf2f(oh));
        w = (unsigned)eh | ((unsigned)oh << 16);
        *(unsigned int*)&lds[16384 + pl] = w;
        // v -> VT
        eh = f2bf(ve[j]); oh = f2bf(vo[j]);
        w = (unsigned)eh | ((unsigned)oh << 16);
        *(unsigned int*)&lds[32768 + ph] = w;
        eh = f2bf(ve[j] - bf2f(eh)); oh = f2bf(vo[j] - bf2f(oh));
        w = (unsigned)eh | ((unsigned)oh << 16);
        *(unsigned int*)&lds[32768 + pl] = w;
      }
    }
  }
  __syncthreads();

  // ---- Phase 3: MFMA sweep ----
  {
    const int wid = t >> 6, lane = t & 63;
    const int s = wid >> 1, dh = wid & 1;
    const int fr = lane & 15, fq = lane >> 4;
    const unsigned short* AT = lds + s * 16384;   // GT (s=0) or MT (s=1)
    const unsigned short* VT = lds + 32768;
    f4 acc[2][4] = {};
    #pragma unroll
    for (int ks = 0; ks < 12; ++ks) {
      const int seg = ks >> 2, loc = ks & 3;
      const int ac = loc * 32 + fq * 8 + ((seg == 2) ? 128 : 0);
      const int bc = loc * 32 + fq * 8 + ((seg == 1) ? 128 : 0);
      s8 aF[2], bF[4];
      #pragma unroll
      for (int m = 0; m < 2; ++m) {
        const int row = dh * 32 + m * 16 + fr;
        aF[m] = *(const s8*)&AT[row * 256 + ((ac >> 3) ^ (row & 7)) * 8 + (ac & 7)];
      }
      #pragma unroll
      for (int n = 0; n < 4; ++n) {
        const int row = n * 16 + fr;
        bF[n] = *(const s8*)&VT[row * 256 + ((bc >> 3) ^ (row & 7)) * 8 + (bc & 7)];
      }
      #pragma unroll
      for (int m = 0; m < 2; ++m)
        #pragma unroll
        for (int n = 0; n < 4; ++n)
          acc[m][n] = __builtin_amdgcn_mfma_f32_16x16x32_bf16(
              aF[m], bF[n], acc[m][n], 0, 0, 0);
    }
    float* Sp = (s == 0) ? Spart : SMpart;
    const size_t pb = ((size_t)(c * 64 + bh)) * 4096;
    #pragma unroll
    for (int m = 0; m < 2; ++m)
      #pragma unroll
      for (int n = 0; n < 4; ++n)
        #pragma unroll
        for (int r = 0; r < 4; ++r) {
          const int d  = dh * 32 + m * 16 + fq * 4 + r;
          const int vv = n * 16 + fr;
          Sp[pb + d * 64 + vv] = acc[m][n][r];
        }
  }

  // ---- ksum/kmsum: row-sums of GT/MT (hi+lo) ----
  if (t < 128) {
    const int isM = t >> 6, d = t & 63;
    const unsigned short* R = lds + isM * 16384 + d * 256;
    const int x7 = d & 7;
    float sum = 0.f;
    #pragma unroll
    for (int sl = 0; sl < 32; ++sl) {
      s8 w8 = *(const s8*)&R[(sl ^ x7) * 8];
      #pragma unroll
      for (int e = 0; e < 8; ++e)
        sum += bf2f((unsigned short)w8[e]);
    }
    (isM ? kmpart : kpart)[(c * 64 + bh) * 64 + d] = sum;
  }
}

// ---------------------------------------------------------------------------
// Kernel 3: reduce 32 partials (deterministic).  grid (64 bh, 4 segs).
// ---------------------------------------------------------------------------
__global__ __launch_bounds__(256) void state_reduce(
    const float* __restrict__ Spart, const float* __restrict__ SMpart,
    const float* __restrict__ kpart, const float* __restrict__ kmpart,
    float* __restrict__ S, float* __restrict__ Sm,
    float* __restrict__ ksum, float* __restrict__ kmsum)
{
  int bh = blockIdx.x, seg = blockIdx.y, t = threadIdx.x;
  int idx = seg * 1024 + t * 4;
  float4 s = {0,0,0,0}, sm = {0,0,0,0};
  #pragma unroll
  for (int p = 0; p < 32; ++p) {
    float4 a = *(const float4*)&Spart [((size_t)(p*64 + bh))*4096 + idx];
    float4 c = *(const float4*)&SMpart[((size_t)(p*64 + bh))*4096 + idx];
    s.x += a.x; s.y += a.y; s.z += a.z; s.w += a.w;
    sm.x += c.x; sm.y += c.y; sm.z += c.z; sm.w += c.w;
  }
  *(float4*)&S [(size_t)bh*4096 + idx] = s;
  *(float4*)&Sm[(size_t)bh*4096 + idx] = sm;
  if (seg == 0 && t < 64) {
    float a = 0.f, c = 0.f;
    #pragma unroll
    for (int p = 0; p < 32; ++p) {
      a += kpart [(p*64 + bh)*64 + t];
      c += kmpart[(p*64 + bh)*64 + t];
    }
    ksum [bh*64 + t] = a;
    kmsum[bh*64 + t] = c;
  }
}

// ---------------------------------------------------------------------------
// Kernel 4: output.  128 threads: 16 l-groups x 8 v-groups, 4l x 8v tile.
// S/Sm read from GLOBAL in-loop (32 KB per bh -> L1-resident after first
// kk sweep).  LDS only Gq/Gm (32 KB) -> ~4 blocks/CU for latency hiding.
// ---------------------------------------------------------------------------
__global__ __launch_bounds__(128, 4) void out_kernel(
    const float* __restrict__ q,
    const float* __restrict__ S, const float* __restrict__ Sm,
    const float* __restrict__ ksum, const float* __restrict__ kmsum,
    float* __restrict__ out)
{
  int bh = blockIdx.x; int b = bh >> 4, h = bh & 15;
  int l0 = blockIdx.y * 64;
  __shared__ float Gq[64][64], Gm[64][64];   // [dd][l]
  int t = threadIdx.x;

  // q -> gfun -> transposed LDS.  lr=t>>1 (row), dq=(t&1)*32 (col half).
  int lr = t >> 1, dq = (t & 1) * 32;
  const float4* qp = (const float4*)(q + (size_t)(b*L_ + l0 + lr)*E_ + h*64 + dq);
  #pragma unroll
  for (int j = 0; j < 8; ++j) {
    float4 qv = qp[j];
    float vals[4] = {qv.x, qv.y, qv.z, qv.w};
    #pragma unroll
    for (int jj = 0; jj < 4; ++jj) {
      int dd = dq + j*4 + jj;
      Gq[dd][lr] = gfun(vals[jj]);
      Gm[dd][lr] = gfun(-vals[jj]);
    }
  }
  __syncthreads();

  int tn = (t & 7) * 8, tm = (t >> 3) * 4;
  const float* Sp   = S  + (size_t)bh*4096;
  const float* Smp  = Sm + (size_t)bh*4096;
  const float* ksp  = ksum  + bh*64;
  const float* kmsp = kmsum + bh*64;
  float acc[4][8] = {};
  float den[4] = {};
  #pragma unroll 2
  for (int kk = 0; kk < 64; ++kk) {
    float4 ga = *(const float4*)&Gq[kk][tm];
    float4 ma = *(const float4*)&Gm[kk][tm];
    float4 s0 = *(const float4*)&Sp [kk*64 + tn];
    float4 s1 = *(const float4*)&Sp [kk*64 + tn + 4];
    float4 m0 = *(const float4*)&Smp[kk*64 + tn];
    float4 m1 = *(const float4*)&Smp[kk*64 + tn + 4];
    float ksv = ksp[kk], kmv = kmsp[kk];
    float gv[4] = {ga.x, ga.y, ga.z, ga.w};
    float mv[4] = {ma.x, ma.y, ma.z, ma.w};
    float sv[8] = {s0.x, s0.y, s0.z, s0.w, s1.x, s1.y, s1.z, s1.w};
    float smv[8] = {m0.x, m0.y, m0.z, m0.w, m1.x, m1.y, m1.z, m1.w};
    #pragma unroll
    for (int i = 0; i < 4; ++i) {
      #pragma unroll
      for (int j = 0; j < 8; ++j)
        acc[i][j] += gv[i]*sv[j] + mv[i]*smv[j];
      den[i] += gv[i]*ksv + mv[i]*kmv;
    }
  }

  #pragma unroll
  for (int i = 0; i < 4; ++i) {
    float r = 1.0f / (den[i] + 1e-6f);
    float4 o0, o1;
    o0.x = acc[i][0]*r; o0.y = acc[i][1]*r; o0.z = acc[i][2]*r; o0.w = acc[i][3]*r;
    o1.x = acc[i][4]*r; o1.y = acc[i][5]*r; o1.z = acc[i][6]*r; o1.w = acc[i][7]*r;
    size_t ro = (size_t)(b*L_ + l0 + tm + i)*E_ + h*64 + tn;
    *(float4*)(out + ro)     = o0;
    *(float4*)(out + ro + 4) = o1;
  }
}

// ---------------------------------------------------------------------------
// Workspace layout (float units):
//   q      : 0          (+16,777,216)
//   k      : 16,777,216 (+16,777,216)
//   qg     : 33,554,432 (+4096)  \
//   denom  : 33,558,528 (+64)     | zeroed by one hipMemsetAsync (8256 fl)
//   xsum   : 33,558,592 (+4096)  /
//   S      : 33,562,688 (+262,144)
//   Sm     : 33,824,832 (+262,144)
//   ksum   : 34,086,976 (+4096)
//   kmsum  : 34,091,072 (+4096)
//   aexp   : 34,095,168 (+262,144)
//   Ah     : f-off 34,357,312 (ushort 33,554,432 = 16,777,216 fl)
//   Bt     : f-off 51,134,528 (ushort  6,291,456 =  3,145,728 fl)
//   end 54,280,256 fl = 217.1 MB
//   Overlays (dead after qkv_mfma): Spart @34,357,312 (+8,388,608),
//   SMpart @42,745,920 (+8,388,608) [= Ah region exactly], kpart @51,134,528
//   (+131,072), kmpart @51,265,600 (+131,072) [inside Bt region].
//   v lives in d_out (consumed by state_part, overwritten by out_kernel).
// ---------------------------------------------------------------------------
extern "C" void kernel_launch(void* const* d_in, const int* in_sizes, int n_in,
                              void* d_out, int out_size, void* d_ws, size_t ws_size,
                              hipStream_t stream) {
  const float* x  = (const float*)d_in[0];
  const float* Wq = (const float*)d_in[1];
  const float* bq = (const float*)d_in[2];
  const float* Wk = (const float*)d_in[3];
  const float* bk = (const float*)d_in[4];
  const float* Wv = (const float*)d_in[5];
  const float* bv = (const float*)d_in[6];
  float* out = (float*)d_out;
  float* ws  = (float*)d_ws;

  float* q      = ws;
  float* k      = ws + 16777216;
  float* qg     = ws + 33554432;
  float* denom  = ws + 33558528;
  float* xsum   = ws + 33558592;
  float* S      = ws + 33562688;
  float* Sm     = ws + 33824832;
  float* ksum   = ws + 34086976;
  float* kmsum  = ws + 34091072;
  float* aexp   = ws + 34095168;
  unsigned short* Ah = (unsigned short*)(ws + 34357312);
  unsigned short* Bt = (unsigned short*)(ws + 51134528);
  float* Spart  = ws + 34357312;   // overlays Ah (dead after qkv_mfma)
  float* SMpart = ws + 42745920;
  float* kpart  = ws + 51134528;   // overlays Bt (dead after qkv_mfma)
  float* kmpart = ws + 51265600;
  float* v      = out;

  hipMemsetAsync(qg, 0, 8256 * sizeof(float), stream);

  split_x<<<256, 256, 0, stream>>>(x, Ah, xsum);
  split_wT<<<dim3(32, 32, 3), 256, 0, stream>>>(Wq, Wk, Wv, bq, xsum, Bt, qg);
  qkv_mfma<<<dim3(768), 512, 0, stream>>>(Ah, Bt, bq, bk, bv, qg,
                                          aexp, denom, q, k, v);
  state_part<<<dim3(B_*H_, 32), 256, 0, stream>>>(k, v, aexp, denom,
                                                  Spart, SMpart, kpart, kmpart);
  state_reduce<<<dim3(B_*H_, 4), 256, 0, stream>>>(Spart, SMpart, kpart, kmpart,
                                                   S, Sm, ksum, kmsum);
  out_kernel<<<dim3(B_*H_, 64), 128, 0, stream>>>(q, S, Sm, ksum, kmsum, out);
}

// Round 5
// 653.932 us; speedup vs baseline: 1.0345x; 1.0345x over previous
//
#include <hip/hip_runtime.h>
#include <hip/hip_bf16.h>
#include <math.h>

// Problem constants
#define B_ 4
#define L_ 4096
#define E_ 1024
#define H_ 16
#define D_ 64
#define M_ (B_*L_)   // 16384 rows

typedef __attribute__((ext_vector_type(8))) short s8;     // 8 bf16 (4 VGPRs)
typedef __attribute__((ext_vector_type(4))) float f4;     // MFMA C/D

// g(x) = (softplus(5x)/5)^2 via HW v_exp/v_log; clamp z<=60 (no overflow).
__device__ __forceinline__ float gfun(float x) {
  float z = fminf(5.0f * x, 60.0f);
  float sp = 0.2f * __logf(1.0f + __expf(z));
  return sp * sp;
}

__device__ __forceinline__ unsigned short f2bf(float v) {
  __hip_bfloat16 h = __float2bfloat16(v);
  return *reinterpret_cast<unsigned short*>(&h);
}
__device__ __forceinline__ float bf2f(unsigned short u) {
  __hip_bfloat16 h = *reinterpret_cast<__hip_bfloat16*>(&u);
  return __bfloat162float(h);
}

// async global->LDS, 16 B per lane
__device__ __forceinline__ void gload16(const void* g, void* l) {
  __builtin_amdgcn_global_load_lds(
      (const __attribute__((address_space(1))) void*)g,
      (__attribute__((address_space(3))) void*)l, 16, 0, 0);
}

// ---------------------------------------------------------------------------
// Prep 1: split x into bf16 hi|lo -> Ah [16384,2048], AND accumulate per-b
// column sums (xsum[b][e]) for the q-global path.  grid 256 blocks x 256 thr;
// block = 64 rows of one b; thread = one float4 column group.
// ---------------------------------------------------------------------------
__global__ __launch_bounds__(256) void split_x(
    const float* __restrict__ x, unsigned short* __restrict__ Ah,
    float* __restrict__ xsum)
{
  int blk = blockIdx.x, t = threadIdx.x;
  int r0 = blk * 64, b = r0 >> 12;
  int c4 = t * 4;
  float4 cs = {0.f, 0.f, 0.f, 0.f};
  for (int r = 0; r < 64; ++r) {
    int row = r0 + r;
    float4 x4 = *(const float4*)(x + (size_t)row * E_ + c4);
    ushort4 hi, lo;
    unsigned short h;
    h = f2bf(x4.x); hi.x = h; lo.x = f2bf(x4.x - bf2f(h));
    h = f2bf(x4.y); hi.y = h; lo.y = f2bf(x4.y - bf2f(h));
    h = f2bf(x4.z); hi.z = h; lo.z = f2bf(x4.z - bf2f(h));
    h = f2bf(x4.w); hi.w = h; lo.w = f2bf(x4.w - bf2f(h));
    *(ushort4*)&Ah[(size_t)row * 2048 + c4]        = hi;
    *(ushort4*)&Ah[(size_t)row * 2048 + 1024 + c4] = lo;
    cs.x += x4.x; cs.y += x4.y; cs.z += x4.z; cs.w += x4.w;
  }
  atomicAdd(&xsum[b * E_ + c4 + 0], cs.x);
  atomicAdd(&xsum[b * E_ + c4 + 1], cs.y);
  atomicAdd(&xsum[b * E_ + c4 + 2], cs.z);
  atomicAdd(&xsum[b * E_ + c4 + 3], cs.w);
}

// ---------------------------------------------------------------------------
// Prep 2: transpose + split each W -> Bt[z] [1024,2048] bf16 (hi|lo).
// z==0 blocks also finish qg: qg[b][n] += (sum_k xsum[b][k]*Wq[k][n])/(L*8)
// (+ bq[n]/8 from the k0==0 blocks).  Wq tile already in LDS.
// ---------------------------------------------------------------------------
__global__ __launch_bounds__(256) void split_wT(
    const float* __restrict__ Wq, const float* __restrict__ Wk,
    const float* __restrict__ Wv, const float* __restrict__ bq,
    const float* __restrict__ xsum,
    unsigned short* __restrict__ Bt, float* __restrict__ qg)
{
  int z = blockIdx.z;
  const float* W = (z == 0) ? Wq : (z == 1) ? Wk : Wv;
  __shared__ float tile[32][33];
  int t = threadIdx.x;
  int tx = t & 31, ty = t >> 5;                    // ty 0..7
  int k0 = blockIdx.x * 32, n0 = blockIdx.y * 32;
  #pragma unroll
  for (int i = 0; i < 4; ++i)
    tile[ty + i*8][tx] = W[(size_t)(k0 + ty + i*8) * 1024 + n0 + tx];
  __syncthreads();
  unsigned short* Bz = Bt + (size_t)z * 2097152;
  #pragma unroll
  for (int i = 0; i < 4; ++i) {
    int n = n0 + ty + i*8, kk = k0 + tx;
    float v = tile[tx][ty + i*8];
    unsigned short h = f2bf(v);
    Bz[(size_t)n * 2048 + kk]        = h;
    Bz[(size_t)n * 2048 + 1024 + kk] = f2bf(v - bf2f(h));
  }
  if (z == 0 && t < 128) {
    int n = t & 31, b = t >> 5;
    float dot = 0.f;
    #pragma unroll
    for (int kk = 0; kk < 32; ++kk)
      dot += xsum[b * E_ + k0 + kk] * tile[kk][n];
    float val = dot * (1.0f / (L_ * 8.0f));
    if (k0 == 0) val += bq[n0 + n] * 0.125f;
    atomicAdd(&qg[b * E_ + n0 + n], val);
  }
}

// ---------------------------------------------------------------------------
// Kernel 1: fused QKV, 256x256-tile / BK=64 / 8-wave, R5: TWO raw s_barriers
// per K-tile + counted vmcnt (AITER-shape: loads interleave MFMA, vmcnt never
// 0 mid-loop).  Raw s_barrier (not __syncthreads) => no implicit vmcnt drain.
//
// Grid: 768 blocks x 512 thr = 1 blk/CU (128 KiB LDS), exactly 3 rounds.
// XCD swizzle: xc = li&7; per-XCD order z-outer (32 blocks = 8 m x 4 n per z)
// so one z's B matrix (4 MB) stays L2-resident while A streams.
//
// LDS (bytes): A0 [0,32K) A1 [32K,64K) B0 [64K,96K) B1 [96K,128K)
// each tile = [256 rows][64 k] bf16, row = 128 B, col-slot (16 B) swizzled by
// slot ^= row&7.  global_load_lds writes linearly -> inverse swizzle applied
// to the per-lane GLOBAL source column; ds_read applies the same XOR (#21).
//
// R5 tile plan (2 barriers, numerics identical to R2-R4):
//   T1: LDA(0)+LDB(0)+LDB(1) [16 b128] -> lgkm0(own) -> MFMA Q(0,0),Q(0,1)
//   T2: LDA(1) [8 b128] -> BARR(#1: all consumer reads of buf issued before
//       any stage-write can land; LDS FIFO serves earlier reads first)
//       -> lgkm0 -> STAGE_B(t+2)+STAGE_A(t+2) -> MFMA Q(1,0),Q(1,1)
//       -> vmcnt(8) -> BARR(#2: every wave's counted stages landed =>
//       tile t+1 fully resident for next T1)
// Ledger: prologue B0 A0 B1 A1 (16 loads) -> vmcnt(8) = tile0 landed.
//   end-of-tile vmcnt(8) leaves exactly {B,A}(t+2) in flight.
//   Peeled last two tiles: no stages, vmcnt(0) drains.
//
// z==1 epilogue: wave tile = 128 rows x one head; logit = qg . k via 4-step
// fr-butterfly; aexp=exp(logit), denom += (fr==0 lanes).
// ---------------------------------------------------------------------------
#define PRIO1() __builtin_amdgcn_s_setprio(1)
#define PRIO0() __builtin_amdgcn_s_setprio(0)
#define BARR() do { asm volatile("" ::: "memory"); \
                    __builtin_amdgcn_s_barrier(); \
                    asm volatile("" ::: "memory"); } while (0)
#define WAITL0() asm volatile("s_waitcnt lgkmcnt(0)" ::: "memory")
#define WAITV(n) asm volatile("s_waitcnt vmcnt(" n ")" ::: "memory")

#define STAGE_A(buf, kofs) do { \
  const unsigned short* g_ = gA + (kofs); \
  char* d_ = dA0 + (buf) * 32768; \
  gload16(g_,          d_); \
  gload16(g_ + 131072, d_ +  8192); \
  gload16(g_ + 262144, d_ + 16384); \
  gload16(g_ + 393216, d_ + 24576); \
} while (0)

#define STAGE_B(buf, kofs) do { \
  const unsigned short* g_ = gB + (kofs); \
  char* d_ = dB0 + (buf) * 32768; \
  gload16(g_,          d_); \
  gload16(g_ + 131072, d_ +  8192); \
  gload16(g_ + 262144, d_ + 16384); \
  gload16(g_ + 393216, d_ + 24576); \
} while (0)

#define LDA(buf, mh) do { \
  const char* p_ = shb + (buf) * 32768 + arow + (mh) * 8192; \
  _Pragma("unroll") \
  for (int ii = 0; ii < 4; ++ii) { \
    aF[ii][0] = *(const s8*)(p_ + ii * 2048 + c0); \
    aF[ii][1] = *(const s8*)(p_ + ii * 2048 + c1); \
  } \
} while (0)

#define LDB(buf, nh) do { \
  const char* p_ = shb + 65536 + (buf) * 32768 + brow + (nh) * 4096; \
  _Pragma("unroll") \
  for (int jj = 0; jj < 2; ++jj) { \
    bF[(nh)*2+jj][0] = *(const s8*)(p_ + jj * 2048 + c0); \
    bF[(nh)*2+jj][1] = *(const s8*)(p_ + jj * 2048 + c1); \
  } \
} while (0)

#define MFMAQ(mh, nh) do { \
  _Pragma("unroll") \
  for (int ii = 0; ii < 4; ++ii) \
    _Pragma("unroll") \
    for (int jj = 0; jj < 2; ++jj) { \
      acc[(mh)*4+ii][(nh)*2+jj] = __builtin_amdgcn_mfma_f32_16x16x32_bf16( \
          aF[ii][0], bF[(nh)*2+jj][0], acc[(mh)*4+ii][(nh)*2+jj], 0, 0, 0); \
      acc[(mh)*4+ii][(nh)*2+jj] = __builtin_amdgcn_mfma_f32_16x16x32_bf16( \
          aF[ii][1], bF[(nh)*2+jj][1], acc[(mh)*4+ii][(nh)*2+jj], 0, 0, 0); \
    } \
} while (0)

// One K-tile in buffer `buf`, 2 barriers total; stages (if doStage) target
// tile kofs pair; vmN = vmcnt immediate (string) at tile end.
#define TILE2(buf, doStage, kB_, kA_, vmN) do { \
  /* T1: A-half0 + both B halves; own-wave wait; first 32 MFMA */ \
  LDA(buf, 0); LDB(buf, 0); LDB(buf, 1); \
  WAITL0(); \
  PRIO1(); MFMAQ(0, 0); MFMAQ(0, 1); PRIO0(); \
  /* T2: A-half1; WAR barrier; stages; last 32 MFMA; counted vmcnt; barrier */ \
  LDA(buf, 1); \
  BARR(); \
  WAITL0(); \
  if (doStage) { STAGE_B(buf, kB_); STAGE_A(buf, kA_); } \
  PRIO1(); MFMAQ(1, 0); MFMAQ(1, 1); PRIO0(); \
  WAITV(vmN); \
  BARR(); \
} while (0)

__global__ __launch_bounds__(512, 2) void qkv_mfma(
    const unsigned short* __restrict__ Ah, const unsigned short* __restrict__ Bt,
    const float* __restrict__ bq, const float* __restrict__ bk,
    const float* __restrict__ bv, const float* __restrict__ qg,
    float* __restrict__ aexp, float* __restrict__ denom,
    float* __restrict__ qo, float* __restrict__ ko, float* __restrict__ vo)
{
  __shared__ unsigned short sh[65536];   // 128 KiB

  const int t  = threadIdx.x;
  const int li = blockIdx.x;            // 0..767
  const int xc = li & 7;
  const int idx = li >> 3;              // 0..95 within XCD
  const int z   = idx >> 5;             // 0..2 (z-outer per XCD)
  const int rem = idx & 31;
  const int bm = (xc * 8 + (rem >> 2)) * 256;
  const int bn = (rem & 3) * 256;

  const float* bias = (z == 0) ? bq : (z == 1) ? bk : bv;
  float* out = (z == 0) ? qo : (z == 1) ? ko : vo;
  const unsigned short* Bz = Bt + (size_t)z * 2097152;

  // staging: thread t writes LDS bytes [region + t*16); physical (row,slot) =
  // (t>>3 + 64*ld, t&7).  Source column is the inverse-swizzled slot.
  const int srow = t >> 3;
  const int scol = ((t & 7) ^ (srow & 7)) * 8;        // elements
  const unsigned short* gA = Ah + (size_t)(bm + srow) * 2048 + scol;
  const unsigned short* gB = Bz + (size_t)(bn + srow) * 2048 + scol;
  char* const shb = (char*)sh;
  char* const dA0 = shb +         t * 16;
  char* const dB0 = shb + 65536 + t * 16;

  // compute mapping: 8 waves = 2M x 4N, wave tile 128x64
  const int lane = t & 63, wid = t >> 6;
  const int wm = wid >> 2, wn = wid & 3;
  const int fr = lane & 15, fq = lane >> 4;
  const int c0 = ((fq)     ^ (fr & 7)) * 16;          // kk=0 swizzled col byte
  const int c1 = ((fq + 4) ^ (fr & 7)) * 16;          // kk=1
  const int arow = (wm * 128 + fr) * 128;
  const int brow = (wn *  64 + fr) * 128;

  f4 acc[8][4] = {};
  s8 aF[4][2], bF[4][2];

  // prologue: tiles 0 (buf0) and 1 (buf1)
  STAGE_B(0, 0);  STAGE_A(0, 0);
  STAGE_B(1, 64); STAGE_A(1, 64);
  WAITV("8");
  BARR();

  // K' = 3072 = 48 tiles of 64; seg map: A cols [hi,hi,lo], B cols [hi,lo,hi]
  #pragma unroll 1
  for (int it = 0; it < 23; ++it) {
    const int t2 = 2 * it + 2, t3 = 2 * it + 3;
    const int kA2 = (t2 < 16) ? t2 * 64 : t2 * 64 - 1024;
    const int kB2 = (t2 < 32) ? t2 * 64 : t2 * 64 - 2048;
    const int kA3 = (t3 < 16) ? t3 * 64 : t3 * 64 - 1024;
    const int kB3 = (t3 < 32) ? t3 * 64 : t3 * 64 - 2048;
    TILE2(0, true, kB2, kA2, "8");
    TILE2(1, true, kB3, kA3, "8");
  }
  // peeled final iteration: tiles 46, 47 — no stages, drain
  TILE2(0, false, 0, 0, "0");
  TILE2(1, false, 0, 0, "0");

  // epilogue: C += bias, store
  float bv4[4];
  #pragma unroll
  for (int j = 0; j < 4; ++j) bv4[j] = bias[bn + wn * 64 + j * 16 + fr];
  #pragma unroll
  for (int i = 0; i < 8; ++i) {
    const int mrow = bm + wm * 128 + i * 16 + fq * 4;
    #pragma unroll
    for (int j = 0; j < 4; ++j) {
      const int ncol = bn + wn * 64 + j * 16 + fr;
      #pragma unroll
      for (int r = 0; r < 4; ++r)
        out[(size_t)(mrow + r) * E_ + ncol] = acc[i][j][r] + bv4[j];
    }
  }

  if (z == 1) {
    // alpha epilogue: this wave's 128 rows x head (bn>>6)+wn
    const int b_ = bm >> 12;
    const int h  = (bn >> 6) + wn;
    const int bh = b_ * 16 + h;
    float qgv[4];
    #pragma unroll
    for (int j = 0; j < 4; ++j) qgv[j] = qg[bh * 64 + j * 16 + fr];
    float partial[8][4];
    #pragma unroll
    for (int i = 0; i < 8; ++i)
      #pragma unroll
      for (int r = 0; r < 4; ++r) {
        float p = 0.f;
        #pragma unroll
        for (int j = 0; j < 4; ++j)
          p += qgv[j] * (acc[i][j][r] + bv4[j]);
        p += __shfl_xor(p, 1);
        p += __shfl_xor(p, 2);
        p += __shfl_xor(p, 4);
        p += __shfl_xor(p, 8);
        partial[i][r] = p;
      }
    if (fr == 0) {
      const int lbase = (bm & 4095) + wm * 128 + fq * 4;
      float s = 0.f;
      #pragma unroll
      for (int i = 0; i < 8; ++i)
        #pragma unroll
        for (int r = 0; r < 4; ++r) {
          float e = __expf(partial[i][r]);
          aexp[(size_t)bh * 4096 + lbase + i * 16 + r] = e;
          s += e;
        }
      atomicAdd(&denom[bh], s);
    }
  }
}

// ---------------------------------------------------------------------------
// Kernel 2 (reverted to R3): KV-state partials, no atomics.
// grid (64 bh, 16 chunks of 256 l); 2 l-teams x (16 d-groups x 8 v-groups);
// 4d x 8v register tile per thread.  Double-buffered 12 KB tiles -> ONE
// __syncthreads per 16-row step; global loads for step i+1 hide under step
// i's FMA block (ping-pong WAR safe by the single barrier).
// ---------------------------------------------------------------------------
__global__ __launch_bounds__(256) void state_part(
    const float* __restrict__ k, const float* __restrict__ v,
    const float* __restrict__ aexp, const float* __restrict__ denom,
    float* __restrict__ Spart, float* __restrict__ SMpart,
    float* __restrict__ kpart, float* __restrict__ kmpart)
{
  int bh = blockIdx.x; int b = bh >> 4, h = bh & 15;
  int c = blockIdx.y;
  int l0 = c * 256;
  float scale = (float)L_ / denom[bh];
  __shared__ float gk[2][16][64], gmk[2][16][64], vt[2][16][64];
  int t = threadIdx.x;
  int lr = t >> 4, cc = (t & 15) * 4;                   // staging role
  int vg = (t & 7) * 8, dg = ((t >> 3) & 15) * 4, team = t >> 7;
  float acc[4][8] = {}, accm[4][8] = {};
  float sgk[4] = {}, sgmk[4] = {};

  for (int lt = 0; lt < 256; lt += 16) {
    int cur = (lt >> 4) & 1;
    int l = l0 + lt + lr;
    size_t off = (size_t)(b*L_ + l) * E_ + h*64 + cc;
    float4 k4 = *(const float4*)(k + off);
    float4 v4 = *(const float4*)(v + off);
    float av = aexp[(size_t)bh * L_ + l] * scale;
    float4 g4, m4;
    g4.x = gfun( k4.x*av); m4.x = gfun(-k4.x*av);
    g4.y = gfun( k4.y*av); m4.y = gfun(-k4.y*av);
    g4.z = gfun( k4.z*av); m4.z = gfun(-k4.z*av);
    g4.w = gfun( k4.w*av); m4.w = gfun(-k4.w*av);
    *(float4*)&gk [cur][lr][cc] = g4;
    *(float4*)&gmk[cur][lr][cc] = m4;
    *(float4*)&vt [cur][lr][cc] = v4;
    __syncthreads();
    #pragma unroll
    for (int l2 = 0; l2 < 8; ++l2) {
      int ls = team * 8 + l2;
      float4 ga = *(float4*)&gk [cur][ls][dg];
      float4 ma = *(float4*)&gmk[cur][ls][dg];
      float4 vA = *(float4*)&vt [cur][ls][vg];
      float4 vB = *(float4*)&vt [cur][ls][vg + 4];
      float gv[4] = {ga.x, ga.y, ga.z, ga.w};
      float mv[4] = {ma.x, ma.y, ma.z, ma.w};
      float vv[8] = {vA.x, vA.y, vA.z, vA.w, vB.x, vB.y, vB.z, vB.w};
      if ((t & 7) == 0) {
        #pragma unroll
        for (int i = 0; i < 4; ++i) { sgk[i] += gv[i]; sgmk[i] += mv[i]; }
      }
      #pragma unroll
      for (int i = 0; i < 4; ++i)
        #pragma unroll
        for (int j = 0; j < 8; ++j) {
          acc [i][j] += gv[i] * vv[j];
          accm[i][j] += mv[i] * vv[j];
        }
    }
  }

  int p = c * 2 + team;                       // 0..31
  size_t pb = ((size_t)(p*64 + bh)) * 4096 + (size_t)dg * 64 + vg;
  #pragma unroll
  for (int i = 0; i < 4; ++i) {
    *(float4*)&Spart [pb + i*64]     = *(float4*)&acc [i][0];
    *(float4*)&Spart [pb + i*64 + 4] = *(float4*)&acc [i][4];
    *(float4*)&SMpart[pb + i*64]     = *(float4*)&accm[i][0];
    *(float4*)&SMpart[pb + i*64 + 4] = *(float4*)&accm[i][4];
  }
  if ((t & 7) == 0) {
    #pragma unroll
    for (int i = 0; i < 4; ++i) {
      kpart [(p*64 + bh)*64 + dg + i] = sgk[i];
      kmpart[(p*64 + bh)*64 + dg + i] = sgmk[i];
    }
  }
}

// ---------------------------------------------------------------------------
// Kernel 3: reduce 32 partials (deterministic).  grid (64 bh, 4 segs).
// ---------------------------------------------------------------------------
__global__ __launch_bounds__(256) void state_reduce(
    const float* __restrict__ Spart, const float* __restrict__ SMpart,
    const float* __restrict__ kpart, const float* __restrict__ kmpart,
    float* __restrict__ S, float* __restrict__ Sm,
    float* __restrict__ ksum, float* __restrict__ kmsum)
{
  int bh = blockIdx.x, seg = blockIdx.y, t = threadIdx.x;
  int idx = seg * 1024 + t * 4;
  float4 s = {0,0,0,0}, sm = {0,0,0,0};
  #pragma unroll
  for (int p = 0; p < 32; ++p) {
    float4 a = *(const float4*)&Spart [((size_t)(p*64 + bh))*4096 + idx];
    float4 c = *(const float4*)&SMpart[((size_t)(p*64 + bh))*4096 + idx];
    s.x += a.x; s.y += a.y; s.z += a.z; s.w += a.w;
    sm.x += c.x; sm.y += c.y; sm.z += c.z; sm.w += c.w;
  }
  *(float4*)&S [(size_t)bh*4096 + idx] = s;
  *(float4*)&Sm[(size_t)bh*4096 + idx] = sm;
  if (seg == 0 && t < 64) {
    float a = 0.f, c = 0.f;
    #pragma unroll
    for (int p = 0; p < 32; ++p) {
      a += kpart [(p*64 + bh)*64 + t];
      c += kmpart[(p*64 + bh)*64 + t];
    }
    ksum [bh*64 + t] = a;
    kmsum[bh*64 + t] = c;
  }
}

// ---------------------------------------------------------------------------
// Kernel 4: output.  128 threads: 16 l-groups x 8 v-groups, 4l x 8v tile.
// S/Sm read from GLOBAL in-loop (32 KB per bh -> L1-resident after first
// kk sweep).  LDS only Gq/Gm (32 KB) -> ~4 blocks/CU for latency hiding.
// ---------------------------------------------------------------------------
__global__ __launch_bounds__(128, 4) void out_kernel(
    const float* __restrict__ q,
    const float* __restrict__ S, const float* __restrict__ Sm,
    const float* __restrict__ ksum, const float* __restrict__ kmsum,
    float* __restrict__ out)
{
  int bh = blockIdx.x; int b = bh >> 4, h = bh & 15;
  int l0 = blockIdx.y * 64;
  __shared__ float Gq[64][64], Gm[64][64];   // [dd][l]
  int t = threadIdx.x;

  // q -> gfun -> transposed LDS.  lr=t>>1 (row), dq=(t&1)*32 (col half).
  int lr = t >> 1, dq = (t & 1) * 32;
  const float4* qp = (const float4*)(q + (size_t)(b*L_ + l0 + lr)*E_ + h*64 + dq);
  #pragma unroll
  for (int j = 0; j < 8; ++j) {
    float4 qv = qp[j];
    float vals[4] = {qv.x, qv.y, qv.z, qv.w};
    #pragma unroll
    for (int jj = 0; jj < 4; ++jj) {
      int dd = dq + j*4 + jj;
      Gq[dd][lr] = gfun(vals[jj]);
      Gm[dd][lr] = gfun(-vals[jj]);
    }
  }
  __syncthreads();

  int tn = (t & 7) * 8, tm = (t >> 3) * 4;
  const float* Sp   = S  + (size_t)bh*4096;
  const float* Smp  = Sm + (size_t)bh*4096;
  const float* ksp  = ksum  + bh*64;
  const float* kmsp = kmsum + bh*64;
  float acc[4][8] = {};
  float den[4] = {};
  #pragma unroll 2
  for (int kk = 0; kk < 64; ++kk) {
    float4 ga = *(const float4*)&Gq[kk][tm];
    float4 ma = *(const float4*)&Gm[kk][tm];
    float4 s0 = *(const float4*)&Sp [kk*64 + tn];
    float4 s1 = *(const float4*)&Sp [kk*64 + tn + 4];
    float4 m0 = *(const float4*)&Smp[kk*64 + tn];
    float4 m1 = *(const float4*)&Smp[kk*64 + tn + 4];
    float ksv = ksp[kk], kmv = kmsp[kk];
    float gv[4] = {ga.x, ga.y, ga.z, ga.w};
    float mv[4] = {ma.x, ma.y, ma.z, ma.w};
    float sv[8] = {s0.x, s0.y, s0.z, s0.w, s1.x, s1.y, s1.z, s1.w};
    float smv[8] = {m0.x, m0.y, m0.z, m0.w, m1.x, m1.y, m1.z, m1.w};
    #pragma unroll
    for (int i = 0; i < 4; ++i) {
      #pragma unroll
      for (int j = 0; j < 8; ++j)
        acc[i][j] += gv[i]*sv[j] + mv[i]*smv[j];
      den[i] += gv[i]*ksv + mv[i]*kmv;
    }
  }

  #pragma unroll
  for (int i = 0; i < 4; ++i) {
    float r = 1.0f / (den[i] + 1e-6f);
    float4 o0, o1;
    o0.x = acc[i][0]*r; o0.y = acc[i][1]*r; o0.z = acc[i][2]*r; o0.w = acc[i][3]*r;
    o1.x = acc[i][4]*r; o1.y = acc[i][5]*r; o1.z = acc[i][6]*r; o1.w = acc[i][7]*r;
    size_t ro = (size_t)(b*L_ + l0 + tm + i)*E_ + h*64 + tn;
    *(float4*)(out + ro)     = o0;
    *(float4*)(out + ro + 4) = o1;
  }
}

// ---------------------------------------------------------------------------
// Workspace layout (float units):
//   q      : 0          (+16,777,216)
//   k      : 16,777,216 (+16,777,216)
//   qg     : 33,554,432 (+4096)  \
//   denom  : 33,558,528 (+64)     | zeroed by one hipMemsetAsync (8256 fl)
//   xsum   : 33,558,592 (+4096)  /
//   S      : 33,562,688 (+262,144)
//   Sm     : 33,824,832 (+262,144)
//   ksum   : 34,086,976 (+4096)
//   kmsum  : 34,091,072 (+4096)
//   aexp   : 34,095,168 (+262,144)
//   Ah     : f-off 34,357,312 (ushort 33,554,432 = 16,777,216 fl)
//   Bt     : f-off 51,134,528 (ushort  6,291,456 =  3,145,728 fl)
//   end 54,280,256 fl = 217.1 MB
//   Overlays (dead after qkv_mfma): Spart @34,357,312 (+8,388,608),
//   SMpart @42,745,920 (+8,388,608) [= Ah region exactly], kpart @51,134,528
//   (+131,072), kmpart @51,265,600 (+131,072) [inside Bt region].
//   v lives in d_out (consumed by state_part, overwritten by out_kernel).
// ---------------------------------------------------------------------------
extern "C" void kernel_launch(void* const* d_in, const int* in_sizes, int n_in,
                              void* d_out, int out_size, void* d_ws, size_t ws_size,
                              hipStream_t stream) {
  const float* x  = (const float*)d_in[0];
  const float* Wq = (const float*)d_in[1];
  const float* bq = (const float*)d_in[2];
  const float* Wk = (const float*)d_in[3];
  const float* bk = (const float*)d_in[4];
  const float* Wv = (const float*)d_in[5];
  const float* bv = (const float*)d_in[6];
  float* out = (float*)d_out;
  float* ws  = (float*)d_ws;

  float* q      = ws;
  float* k      = ws + 16777216;
  float* qg     = ws + 33554432;
  float* denom  = ws + 33558528;
  float* xsum   = ws + 33558592;
  float* S      = ws + 33562688;
  float* Sm     = ws + 33824832;
  float* ksum   = ws + 34086976;
  float* kmsum  = ws + 34091072;
  float* aexp   = ws + 34095168;
  unsigned short* Ah = (unsigned short*)(ws + 34357312);
  unsigned short* Bt = (unsigned short*)(ws + 51134528);
  float* Spart  = ws + 34357312;   // overlays Ah (dead after qkv_mfma)
  float* SMpart = ws + 42745920;
  float* kpart  = ws + 51134528;   // overlays Bt (dead after qkv_mfma)
  float* kmpart = ws + 51265600;
  float* v      = out;

  hipMemsetAsync(qg, 0, 8256 * sizeof(float), stream);

  split_x<<<256, 256, 0, stream>>>(x, Ah, xsum);
  split_wT<<<dim3(32, 32, 3), 256, 0, stream>>>(Wq, Wk, Wv, bq, xsum, Bt, qg);
  qkv_mfma<<<dim3(768), 512, 0, stream>>>(Ah, Bt, bq, bk, bv, qg,
                                          aexp, denom, q, k, v);
  state_part<<<dim3(B_*H_, 16), 256, 0, stream>>>(k, v, aexp, denom,
                                                  Spart, SMpart, kpart, kmpart);
  state_reduce<<<dim3(B_*H_, 4), 256, 0, stream>>>(Spart, SMpart, kpart, kmpart,
                                                   S, Sm, ksum, kmsum);
  out_kernel<<<dim3(B_*H_, 64), 128, 0, stream>>>(q, S, Sm, ksum, kmsum, out);
}